// Round 16
// baseline (42.052 us; speedup 1.0000x reference)
//
#include <hip/hip_runtime.h>

#define H 512
#define W 512
#define BAND 32
#define NBANDS (H / BAND)   // 16
#define NEG_INF (-3.402823466e38f)

__global__ void zero_acc_kernel(double* acc) {
    if (threadIdx.x == 0) acc[0] = 0.0;
}

// One block per (band of 32 output rows, image, tensor); 512 threads = 8 waves.
// Grid 1024 blocks; LDS 33 KB -> 4 blocks/CU -> 32 waves/CU (100% occupancy),
// all blocks resident (R15 was 66 KB double-buffer -> 2 blocks/CU, occ 34%).
// Batches of 16 s-rows; each wave owns TWO rows (slots w, w+8) = 2 independent
// row pipelines per wave. hbuf is SINGLE-buffered: 2 barriers per batch
// (h-ready after writes; reads-done before next batch's writes).
// Per row (wave-local, no LDS): t[8] = 3-row vertical raw sum (6 float4,
// L1/L2-served), s = horizontal 3-sum via 2 halo shuffles (9x-scaled),
// horizontal 17-max via tile prefix/suffix + 16 lane shuffles:
//   h(8L+k) = max(S_{L-1}[k], m_L, P_{L+1}[k]).
// Vertical 17-max: batch == van Herk segment (16): publish h rows, barrier,
// per-column register van Herk (arr[16], Pblk reset each batch, suffix
// transform at batch end). Outputs exist from batch 1 on; 48 rows = 3 batches
// -> 2x16 = 32 outputs = BAND.
// Lessons carried: (R12) full unroll hoists loads -> spill: outer loop
// `#pragma unroll 1`, arr statically indexed. (R13) 64-VGPR cap spills:
// (512,4) = 128-cap; 52 live, zero spill (WRITE_SIZE tell). hbuf split-half
// layout: k=0..3 at [4L], k=4..7 at [256+4L]; writes and column reads are
// conflict-free (the ~590K SQ_LDS_BANK_CONFLICT is ds_permute shuffle
// bookkeeping, not a layout bug).
__global__ __launch_bounds__(512, 4) void fused_kernel(const float* __restrict__ in0,
                                                       const float* __restrict__ in1,
                                                       double* __restrict__ acc) {
    const int band = blockIdx.x;
    const int img  = blockIdx.y;
    const float* __restrict__ im = (blockIdx.z ? in1 : in0) + (size_t)img * H * W;

    const int y0 = band * BAND, y1 = y0 + BAND;
    const int jlo_v = y0 - 8;            // first streamed s-row

    __shared__ float hbuf[16][W];        // single-buffered h rows (split-half)
    __shared__ double wsum[8];

    const int tid  = threadIdx.x;
    const int w    = tid >> 6;           // wave id 0..7
    const int lane = tid & 63;
    const int c0   = lane << 3;          // 8 cols per lane
    // split-half position of column tid inside an hbuf row
    const int pos  = ((tid & 4) ? 256 : 0) + ((tid >> 3) << 2) + (tid & 3);

    float accMax = 0.f, accSum = 0.f;
    float arr[16];                       // van Herk: prev-seg suffix / cur h

// One s-row in slot SLOT (0..15) of batch b. j wave-uniform.
#define ROW(SLOT)                                                              \
    {                                                                          \
        const int j = jb + (SLOT);                                             \
        float h[8];                                                            \
        if (j >= 0 && j < H) {                                                 \
            float t[8];                                                        \
            _Pragma("unroll") for (int k = 0; k < 8; ++k) t[k] = 0.f;          \
            _Pragma("unroll") for (int dr = -1; dr <= 1; ++dr) {               \
                const int r = j + dr;                                          \
                if (r >= 0 && r < H) {          /* wave-uniform */             \
                    const float* rp = im + (size_t)r * W + c0;                 \
                    const float4 a  = *(const float4*)rp;                      \
                    const float4 c4 = *(const float4*)(rp + 4);                \
                    t[0] += a.x;  t[1] += a.y;  t[2] += a.z;  t[3] += a.w;     \
                    t[4] += c4.x; t[5] += c4.y; t[6] += c4.z; t[7] += c4.w;    \
                }                                                              \
            }                                                                  \
            float tl = __shfl_up(t[7], 1);   if (lane == 0)  tl = 0.f;         \
            float tr = __shfl_down(t[0], 1); if (lane == 63) tr = 0.f;         \
            float s[8];                                                        \
            s[0] = tl + t[0] + t[1];                                           \
            _Pragma("unroll") for (int k = 1; k < 7; ++k)                      \
                s[k] = t[k - 1] + t[k] + t[k + 1];                             \
            s[7] = t[6] + t[7] + tr;                                           \
            const int rlo = (j - 8 > y0) ? j - 8 : y0;                         \
            const int rhi = (j + 8 < y1 - 1) ? j + 8 : y1 - 1;                 \
            float rowsum = 0.f;                                                \
            _Pragma("unroll") for (int k = 0; k < 8; ++k) {                    \
                const int col = c0 + k;                                        \
                const int wlo = (col - 8 > 0) ? col - 8 : 0;                   \
                const int whi = (col + 8 < W - 1) ? col + 8 : W - 1;           \
                rowsum += s[k] * (float)(whi - wlo + 1);                       \
            }                                                                  \
            accSum += rowsum * ((float)(rhi - rlo + 1) * (1.f / 289.f));       \
            float p[8];                                                        \
            p[0] = s[0];                                                       \
            _Pragma("unroll") for (int k = 1; k < 8; ++k)                      \
                p[k] = fmaxf(p[k - 1], s[k]);                                  \
            const float m = p[7];                                              \
            float qrun = s[7];                                                 \
            _Pragma("unroll") for (int k = 7; k >= 0; --k) {                   \
                if (k < 7) qrun = fmaxf(qrun, s[k]);                           \
                float qp = __shfl_up(qrun, 1);   if (lane == 0)  qp = NEG_INF; \
                float pn = __shfl_down(p[k], 1); if (lane == 63) pn = NEG_INF; \
                h[k] = fmaxf(fmaxf(qp, m), pn);                                \
            }                                                                  \
        } else {                                                               \
            _Pragma("unroll") for (int k = 0; k < 8; ++k) h[k] = NEG_INF;      \
        }                                                                      \
        {                                                                      \
            float* hw = &hbuf[SLOT][0];                                        \
            *(float4*)&hw[lane << 2]         = make_float4(h[0], h[1], h[2], h[3]); \
            *(float4*)&hw[256 + (lane << 2)] = make_float4(h[4], h[5], h[6], h[7]); \
        }                                                                      \
    }

#pragma unroll 1
    for (int b = 0; b < 3; ++b) {        // 3 batches of 16 s-rows = 48 rows
        const int jb = jlo_v + b * 16;
        ROW(w)                            // slot w
        ROW(w + 8)                        // slot w+8 (independent pipeline)
        __syncthreads();                  // h rows ready

        // ---- stage C: vertical van Herk over this 16-row segment ----
        float Pblk = NEG_INF;
        if (b >= 1) {
#pragma unroll
            for (int r = 0; r < 16; ++r) {
                const float hv = hbuf[r][pos];
                Pblk = fmaxf(Pblk, hv);
                accMax += fmaxf(arr[r], Pblk);
                arr[r] = hv;
            }
        } else {
#pragma unroll
            for (int r = 0; r < 16; ++r) {
                const float hv = hbuf[r][pos];
                Pblk = fmaxf(Pblk, hv);
                arr[r] = hv;
            }
        }
        // segment end: in-place suffix transform arr[r] = max(h[r..15])
#pragma unroll
        for (int rr = 14; rr >= 0; --rr) arr[rr] = fmaxf(arr[rr], arr[rr + 1]);

        if (b != 2) __syncthreads();      // reads done before next batch writes
    }
#undef ROW

    // ---- block reduction (values are 9x-scaled; undo once) ----
    double v = ((double)accMax - (double)accSum) * (1.0 / 9.0);
#pragma unroll
    for (int off = 32; off > 0; off >>= 1) v += __shfl_down(v, off, 64);
    if (lane == 0) wsum[w] = v;
    __syncthreads();
    if (tid == 0) {
        double bsum = 0.0;
#pragma unroll
        for (int wv = 0; wv < 8; ++wv) bsum += wsum[wv];
        atomicAdd(acc, bsum);
    }
}

__global__ void finalize_kernel(const double* __restrict__ acc, float* __restrict__ out) {
    if (threadIdx.x == 0) {
        // total pixels across both tensors = 2*32*512*512 = 16777216
        out[0] = (float)(1.0 - acc[0] * (1.0 / 16777216.0));
    }
}

extern "C" void kernel_launch(void* const* d_in, const int* in_sizes, int n_in,
                              void* d_out, int out_size, void* d_ws, size_t ws_size,
                              hipStream_t stream) {
    const float* in0 = (const float*)d_in[0];
    const float* in1 = (const float*)d_in[1];
    float* out = (float*)d_out;
    double* acc = (double*)d_ws;

    zero_acc_kernel<<<1, 64, 0, stream>>>(acc);
    fused_kernel<<<dim3(NBANDS, 32, 2), 512, 0, stream>>>(in0, in1, acc);
    finalize_kernel<<<1, 64, 0, stream>>>(acc, out);
}

// Round 17
// 34.755 us; speedup vs baseline: 1.2099x; 1.2099x over previous
//
#include <hip/hip_runtime.h>

#define H 512
#define W 512
#define BAND 64
#define NBANDS (H / BAND)   // 8
#define NEG_INF (-3.402823466e38f)

__global__ void zero_acc_kernel(double* acc) {
    if (threadIdx.x == 0) acc[0] = 0.0;
}

// One block per (band of 64 output rows, image, tensor); 512 threads = 8 waves.
// R15 structure (best: 35.1us): batches of 16 s-rows, each wave owns TWO rows
// (slots w, w+8), double-buffered hbuf, ONE barrier per batch, BAND=64
// (1.25x halo), (512,4) no-spill, `#pragma unroll 1` outer loop.
// R17 change: de-serialize the horizontal-max shuffles. R15's k-loop computed
// qrun (dependent fmax) then shfl_up(qrun) per iteration -> 8 SERIAL shuffle
// latencies (~240 cyc/row) on the critical path (VALUBusy 26%). Now: suffix
// array q[8] first (7 fmax chain), THEN all 16 shuffles issued independent
// (8 shfl_up(q[k]) + 8 shfl_down(p[k])), then combine
//   h(8L+k) = max(q_{L-1}[k], m_L, p_{L+1}[k]).
// 16 shuffle latencies overlap each other and across the wave's 2 row
// pipelines (32 in flight).
// R16 lesson: BAND=32 + single-buffer regressed (extra barrier re-serialized;
// halo 1.5x; occupancy only 34->41) -> residency is not the limiter, the
// dependent chain is.
// hbuf split-half layout: k=0..3 at [4L], k=4..7 at [256+4L]; float4 writes
// and column reads conflict-free (the ~786K SQ_LDS_BANK_CONFLICT is
// ds_permute shuffle bookkeeping, not a layout bug).
__global__ __launch_bounds__(512, 4) void fused_kernel(const float* __restrict__ in0,
                                                       const float* __restrict__ in1,
                                                       double* __restrict__ acc) {
    const int band = blockIdx.x;
    const int img  = blockIdx.y;
    const float* __restrict__ im = (blockIdx.z ? in1 : in0) + (size_t)img * H * W;

    const int y0 = band * BAND, y1 = y0 + BAND;
    const int jlo_v = y0 - 8;            // first streamed s-row

    __shared__ float hbuf[2][16][W];     // double-buffered h rows (split-half)
    __shared__ double wsum[8];

    const int tid  = threadIdx.x;
    const int w    = tid >> 6;           // wave id 0..7
    const int lane = tid & 63;
    const int c0   = lane << 3;          // 8 cols per lane
    // split-half position of column tid inside an hbuf row
    const int pos  = ((tid & 4) ? 256 : 0) + ((tid >> 3) << 2) + (tid & 3);

    float accMax = 0.f, accSum = 0.f;
    float arr[16];                       // van Herk: prev-seg suffix / cur h

// One s-row in slot SLOT (0..15) of batch b. j wave-uniform.
#define ROW(SLOT)                                                              \
    {                                                                          \
        const int j = jb + (SLOT);                                             \
        float h[8];                                                            \
        if (j >= 0 && j < H) {                                                 \
            float t[8];                                                        \
            _Pragma("unroll") for (int k = 0; k < 8; ++k) t[k] = 0.f;          \
            _Pragma("unroll") for (int dr = -1; dr <= 1; ++dr) {               \
                const int r = j + dr;                                          \
                if (r >= 0 && r < H) {          /* wave-uniform */             \
                    const float* rp = im + (size_t)r * W + c0;                 \
                    const float4 a  = *(const float4*)rp;                      \
                    const float4 c4 = *(const float4*)(rp + 4);                \
                    t[0] += a.x;  t[1] += a.y;  t[2] += a.z;  t[3] += a.w;     \
                    t[4] += c4.x; t[5] += c4.y; t[6] += c4.z; t[7] += c4.w;    \
                }                                                              \
            }                                                                  \
            float tl = __shfl_up(t[7], 1);   if (lane == 0)  tl = 0.f;         \
            float tr = __shfl_down(t[0], 1); if (lane == 63) tr = 0.f;         \
            float s[8];                                                        \
            s[0] = tl + t[0] + t[1];                                           \
            _Pragma("unroll") for (int k = 1; k < 7; ++k)                      \
                s[k] = t[k - 1] + t[k] + t[k + 1];                             \
            s[7] = t[6] + t[7] + tr;                                           \
            const int rlo = (j - 8 > y0) ? j - 8 : y0;                         \
            const int rhi = (j + 8 < y1 - 1) ? j + 8 : y1 - 1;                 \
            float rowsum = 0.f;                                                \
            _Pragma("unroll") for (int k = 0; k < 8; ++k) {                    \
                const int col = c0 + k;                                        \
                const int wlo = (col - 8 > 0) ? col - 8 : 0;                   \
                const int whi = (col + 8 < W - 1) ? col + 8 : W - 1;           \
                rowsum += s[k] * (float)(whi - wlo + 1);                       \
            }                                                                  \
            accSum += rowsum * ((float)(rhi - rlo + 1) * (1.f / 289.f));       \
            /* prefix p[k]=max(s[0..k]); suffix q[k]=max(s[k..7]) */           \
            float p[8], qarr[8];                                               \
            p[0] = s[0];                                                       \
            _Pragma("unroll") for (int k = 1; k < 8; ++k)                      \
                p[k] = fmaxf(p[k - 1], s[k]);                                  \
            qarr[7] = s[7];                                                    \
            _Pragma("unroll") for (int k = 6; k >= 0; --k)                     \
                qarr[k] = fmaxf(qarr[k + 1], s[k]);                            \
            const float m = p[7];                                              \
            /* all 16 shuffles independent -> latencies overlap */             \
            float qp[8], pn[8];                                                \
            _Pragma("unroll") for (int k = 0; k < 8; ++k)                      \
                qp[k] = __shfl_up(qarr[k], 1);                                 \
            _Pragma("unroll") for (int k = 0; k < 8; ++k)                      \
                pn[k] = __shfl_down(p[k], 1);                                  \
            _Pragma("unroll") for (int k = 0; k < 8; ++k) {                    \
                if (lane == 0)  qp[k] = NEG_INF;                               \
                if (lane == 63) pn[k] = NEG_INF;                               \
                h[k] = fmaxf(fmaxf(qp[k], m), pn[k]);                          \
            }                                                                  \
        } else {                                                               \
            _Pragma("unroll") for (int k = 0; k < 8; ++k) h[k] = NEG_INF;      \
        }                                                                      \
        {                                                                      \
            float* hw = hwbase + (SLOT) * W;                                   \
            *(float4*)&hw[lane << 2]         = make_float4(h[0], h[1], h[2], h[3]); \
            *(float4*)&hw[256 + (lane << 2)] = make_float4(h[4], h[5], h[6], h[7]); \
        }                                                                      \
    }

#pragma unroll 1
    for (int b = 0; b < 5; ++b) {        // 5 batches of 16 s-rows = 80 rows
        const int jb = jlo_v + b * 16;
        float* hwbase = &hbuf[b & 1][0][0];
        ROW(w)                            // slot w
        ROW(w + 8)                        // slot w+8 (independent pipeline)
        __syncthreads();                  // the ONLY barrier per batch

        // ---- stage C: vertical van Herk over this 16-row segment ----
        const float* hb = hwbase;
        float Pblk = NEG_INF;
        if (b >= 1) {
#pragma unroll
            for (int r = 0; r < 16; ++r) {
                const float hv = hb[r * W + pos];
                Pblk = fmaxf(Pblk, hv);
                accMax += fmaxf(arr[r], Pblk);
                arr[r] = hv;
            }
        } else {
#pragma unroll
            for (int r = 0; r < 16; ++r) {
                const float hv = hb[r * W + pos];
                Pblk = fmaxf(Pblk, hv);
                arr[r] = hv;
            }
        }
        // segment end: in-place suffix transform arr[r] = max(h[r..15])
#pragma unroll
        for (int rr = 14; rr >= 0; --rr) arr[rr] = fmaxf(arr[rr], arr[rr + 1]);
    }
#undef ROW

    // ---- block reduction (values are 9x-scaled; undo once) ----
    double v = ((double)accMax - (double)accSum) * (1.0 / 9.0);
#pragma unroll
    for (int off = 32; off > 0; off >>= 1) v += __shfl_down(v, off, 64);
    if (lane == 0) wsum[w] = v;
    __syncthreads();
    if (tid == 0) {
        double bsum = 0.0;
#pragma unroll
        for (int wv = 0; wv < 8; ++wv) bsum += wsum[wv];
        atomicAdd(acc, bsum);
    }
}

__global__ void finalize_kernel(const double* __restrict__ acc, float* __restrict__ out) {
    if (threadIdx.x == 0) {
        // total pixels across both tensors = 2*32*512*512 = 16777216
        out[0] = (float)(1.0 - acc[0] * (1.0 / 16777216.0));
    }
}

extern "C" void kernel_launch(void* const* d_in, const int* in_sizes, int n_in,
                              void* d_out, int out_size, void* d_ws, size_t ws_size,
                              hipStream_t stream) {
    const float* in0 = (const float*)d_in[0];
    const float* in1 = (const float*)d_in[1];
    float* out = (float*)d_out;
    double* acc = (double*)d_ws;

    zero_acc_kernel<<<1, 64, 0, stream>>>(acc);
    fused_kernel<<<dim3(NBANDS, 32, 2), 512, 0, stream>>>(in0, in1, acc);
    finalize_kernel<<<1, 64, 0, stream>>>(acc, out);
}